// Round 6
// baseline (579.401 us; speedup 1.0000x reference)
//
#include <hip/hip_runtime.h>
#include <hip/hip_cooperative_groups.h>

namespace cg = cooperative_groups;

#define N_NODES 100000
#define N_EDGES 600000
#define NB_SCAN 391   // ceil(N_NODES/256)

typedef __attribute__((ext_vector_type(8))) short short8;   // 8 bf16 (4 VGPRs)
typedef __attribute__((ext_vector_type(4))) float f32x4;    // MFMA accumulator

// round-to-nearest-even f32 -> bf16
__device__ inline unsigned short bf16r(float x) {
    unsigned u = __float_as_uint(x);
    return (unsigned short)((u + 0x7FFFu + ((u >> 16) & 1u)) >> 16);
}
__device__ inline unsigned bf16pack2(float x, float y) {
    unsigned ux = __float_as_uint(x), uy = __float_as_uint(y);
    ux = (ux + 0x7FFFu + ((ux >> 16) & 1u)) >> 16;
    uy = (uy + 0x7FFFu + ((uy >> 16) & 1u)) >> 16;
    return ux | (uy << 16);
}

// ---------------------------------------------------------------------------
// Cooperative setup kernel: zero counters + bf16 weight transposes + degree
// histograms + hierarchical exclusive scan of receiver counts + rsqrt degree
// factors + counting-sort reorder of senders by receiver. Phases separated by
// grid.sync(). Grid: NB_SCAN blocks x 256 (all co-resident).
// ---------------------------------------------------------------------------
__global__ __launch_bounds__(256)
void setup_kernel(const int* __restrict__ senders, const int* __restrict__ receivers,
                  const float* __restrict__ W0, const float* __restrict__ W1,
                  const float* __restrict__ Wmu, const float* __restrict__ Wls,
                  unsigned short* __restrict__ w0t, unsigned short* __restrict__ w1t,
                  unsigned short* __restrict__ wht,
                  int* __restrict__ cnt_s, int* __restrict__ cnt_r,
                  int* __restrict__ offs, int* __restrict__ cursor,
                  int* __restrict__ srt,
                  float* __restrict__ inv_s, float* __restrict__ inv_r,
                  int* __restrict__ bsum) {
    cg::grid_group grid = cg::this_grid();
    __shared__ int a[512], b[512];
    const int t = threadIdx.x;
    const int tid = blockIdx.x * 256 + t;
    const int nt = gridDim.x * 256;

    // P0: zero counters (cnt_s,cnt_r contiguous) + weight prep
    for (int i = tid; i < 2 * N_NODES; i += nt) cnt_s[i] = 0;
    for (int i = tid; i < 65536; i += nt) {
        if (i < 16384) {
            int nn = i >> 7, k = i & 127;
            w0t[i] = bf16r(W0[k * 128 + nn]);
        } else if (i < 32768) {
            int j = i - 16384;
            int nn = j >> 7, k = j & 127;
            w1t[j] = bf16r(W1[k * 128 + nn]);
        } else {
            int j = i - 32768;
            int nn = j >> 8, k = j & 255;
            float v = (nn < 64) ? Wmu[k * 64 + nn] : Wls[k * 64 + (nn - 64)];
            wht[j] = bf16r(v);
        }
    }
    grid.sync();

    // P1: histograms
    for (int e = tid; e < N_EDGES; e += nt) {
        atomicAdd(&cnt_s[senders[e]], 1);
        atomicAdd(&cnt_r[receivers[e]], 1);
    }
    grid.sync();

    // P2: per-chunk exclusive scan of cnt_r (block = chunk)
    if (blockIdx.x < NB_SCAN) {
        const int i = blockIdx.x * 256 + t;
        const int v = (i < N_NODES) ? cnt_r[i] : 0;
        a[t] = v;
        __syncthreads();
        int* pin = a; int* pout = b;
        #pragma unroll
        for (int off = 1; off < 256; off <<= 1) {
            pout[t] = pin[t] + ((t >= off) ? pin[t - off] : 0);
            __syncthreads();
            int* tmp = pin; pin = pout; pout = tmp;
        }
        if (i < N_NODES) offs[i] = pin[t] - v;
        if (t == 255) bsum[blockIdx.x] = pin[255];
    }
    grid.sync();

    // P3: block 0 scans the NB_SCAN block sums (512-slot scan, 2 slots/thread)
    if (blockIdx.x == 0) {
        const int v0 = (t < NB_SCAN) ? bsum[t] : 0;
        const int v1 = (t + 256 < NB_SCAN) ? bsum[t + 256] : 0;
        a[t] = v0; a[t + 256] = v1;
        __syncthreads();
        int* pin = a; int* pout = b;
        #pragma unroll
        for (int off = 1; off < 512; off <<= 1) {
            pout[t]       = pin[t]       + ((t >= off)       ? pin[t - off]       : 0);
            pout[t + 256] = pin[t + 256] + ((t + 256 >= off) ? pin[t + 256 - off] : 0);
            __syncthreads();
            int* tmp = pin; pin = pout; pout = tmp;
        }
        if (t < NB_SCAN) bsum[t] = pin[t] - v0;
        if (t + 256 < NB_SCAN) bsum[t + 256] = pin[t + 256] - v1;
    }
    grid.sync();

    // P4: finalize offsets, cursor, rsqrt degree factors
    for (int i = tid; i < N_NODES; i += nt) {
        int o = offs[i] + bsum[i >> 8];
        offs[i] = o;
        cursor[i] = o;
        inv_s[i] = rsqrtf(fmaxf((float)cnt_s[i], 1.0f));
        inv_r[i] = rsqrtf(fmaxf((float)cnt_r[i], 1.0f));
    }
    if (tid == 0) offs[N_NODES] = N_EDGES;
    grid.sync();

    // P5: reorder (sorted-by-receiver sender list)
    for (int e = tid; e < N_EDGES; e += nt) {
        int pos = atomicAdd(&cursor[receivers[e]], 1);
        srt[pos] = senders[e];
    }
}

// ---------------------------------------------------------------------------
// dst[r] = bf16( scale[r] * sum over incoming edges of src[sender] )
// src/dst: bf16 rows of 128 cols = 16 uint4. Each wave processes 4 receivers
// concurrently in 16-lane groups; lane loads uint4 (16 B) per edge -> 4
// independent row-streams per VMEM instruction.
// ---------------------------------------------------------------------------
__global__ __launch_bounds__(256)
void aggregate_kernel(const uint4* __restrict__ src, uint4* __restrict__ dst,
                      const int* __restrict__ offs, const int* __restrict__ srt,
                      const float* __restrict__ scale, int n) {
    const int lane = threadIdx.x & 63;
    const int wave = threadIdx.x >> 6;
    const int grp  = lane >> 4;          // 0..3 (receiver group within wave)
    const int l16  = lane & 15;
    const int wid  = blockIdx.x * 4 + wave;
    const int nwv  = gridDim.x * 4;
    const unsigned grpbase = lane & 48;  // grp*16, for shfl source

    for (int rb = wid * 4; rb < n; rb += nwv * 4) {   // wave-uniform
        const int r = rb + grp;
        const bool valid = (r < n);
        int beg = 0, deg = 0;
        if (valid) { beg = offs[r]; deg = offs[r + 1] - beg; }
        float ax[8];
        #pragma unroll
        for (int k = 0; k < 8; ++k) ax[k] = 0.0f;

        for (int j0 = 0; ; j0 += 16) {
            const int rem = deg - j0;            // group-uniform
            int wm = rem;                        // wave max remaining
            wm = max(wm, __shfl_xor(wm, 16));
            wm = max(wm, __shfl_xor(wm, 32));
            if (wm <= 0) break;
            const int idx = (j0 + l16 < deg) ? srt[beg + j0 + l16] : 0;
            const int jmax = (wm < 16) ? wm : 16;
            for (int j = 0; j < jmax; ++j) {
                const int s = __shfl(idx, grpbase + j);
                if (j < rem) {
                    const uint4 v = src[(size_t)s * 16 + l16];
                    ax[0] += __uint_as_float(v.x << 16);
                    ax[1] += __uint_as_float(v.x & 0xFFFF0000u);
                    ax[2] += __uint_as_float(v.y << 16);
                    ax[3] += __uint_as_float(v.y & 0xFFFF0000u);
                    ax[4] += __uint_as_float(v.z << 16);
                    ax[5] += __uint_as_float(v.z & 0xFFFF0000u);
                    ax[6] += __uint_as_float(v.w << 16);
                    ax[7] += __uint_as_float(v.w & 0xFFFF0000u);
                }
            }
        }
        if (valid) {
            const float sc = scale[r];
            uint4 o;
            o.x = bf16pack2(ax[0] * sc, ax[1] * sc);
            o.y = bf16pack2(ax[2] * sc, ax[3] * sc);
            o.z = bf16pack2(ax[4] * sc, ax[5] * sc);
            o.w = bf16pack2(ax[6] * sc, ax[7] * sc);
            dst[(size_t)r * 16 + l16] = o;
        }
    }
}

// ---------------------------------------------------------------------------
// MFMA graph-conv layer: y = bf16( softmax(relu(x @ W + b)) * inv_out )
// IN_BF16=false: x is f32 [N,128] (nodes). IN_BF16=true: x is bf16 rows.
// 64-row tile/block, wave w owns cols [32w,32w+32). Output staged back into
// Xl (dead after the MFMAs) and written out as coalesced uint4.
// ---------------------------------------------------------------------------
template<bool IN_BF16>
__global__ __launch_bounds__(256)
void gc_mfma(const void* __restrict__ xv, const unsigned short* __restrict__ Wt,
             const float* __restrict__ bias, const float* __restrict__ inv_out,
             unsigned short* __restrict__ y, int nrows) {
    __shared__ __align__(16) unsigned short Xl[64 * 136];
    __shared__ float sred0[4][64];
    __shared__ float sred1[4][64];
    const int row0 = blockIdx.x * 64;
    if (IN_BF16) {
        const uint2* xs = (const uint2*)xv;          // row = 32 uint2
        for (int c = threadIdx.x; c < 64 * 32; c += 256) {
            int r = c >> 5, cu = c & 31;
            int grow = row0 + r;
            uint2 v = make_uint2(0u, 0u);
            if (grow < nrows) v = xs[(size_t)grow * 32 + cu];
            *((uint2*)&Xl[r * 136] + cu) = v;
        }
    } else {
        const float* x = (const float*)xv;
        for (int c = threadIdx.x; c < 64 * 32; c += 256) {
            int r = c >> 5, c4 = c & 31;
            int grow = row0 + r;
            float4 v = make_float4(0.f, 0.f, 0.f, 0.f);
            if (grow < nrows) v = *(const float4*)&x[(size_t)grow * 128 + c4 * 4];
            *(uint2*)&Xl[r * 136 + c4 * 4] = make_uint2(bf16pack2(v.x, v.y), bf16pack2(v.z, v.w));
        }
    }
    __syncthreads();

    const int lane = threadIdx.x & 63;
    const int w = threadIdx.x >> 6;
    const int q = lane >> 4;
    const int l16 = lane & 15;

    short8 bf[4][2];
    #pragma unroll
    for (int k0 = 0; k0 < 4; ++k0)
        #pragma unroll
        for (int nt = 0; nt < 2; ++nt) {
            int ncol = w * 32 + nt * 16 + l16;
            bf[k0][nt] = *(const short8*)&Wt[ncol * 128 + k0 * 32 + q * 8];
        }

    f32x4 acc[4][2] = {};
    #pragma unroll
    for (int k0 = 0; k0 < 4; ++k0) {
        #pragma unroll
        for (int m = 0; m < 4; ++m) {
            short8 aa = *(const short8*)&Xl[(m * 16 + l16) * 136 + k0 * 32 + q * 8];
            acc[m][0] = __builtin_amdgcn_mfma_f32_16x16x32_bf16(aa, bf[k0][0], acc[m][0], 0, 0, 0);
            acc[m][1] = __builtin_amdgcn_mfma_f32_16x16x32_bf16(aa, bf[k0][1], acc[m][1], 0, 0, 0);
        }
    }

    // bias -> relu -> softmax over 128 cols -> *inv_out -> bf16
    const float bv0 = bias[w * 32 + l16];
    const float bv1 = bias[w * 32 + 16 + l16];
    float v[4][2][4];
    #pragma unroll
    for (int m = 0; m < 4; ++m)
        #pragma unroll
        for (int r = 0; r < 4; ++r) {
            v[m][0][r] = fmaxf(acc[m][0][r] + bv0, 0.0f);
            v[m][1][r] = fmaxf(acc[m][1][r] + bv1, 0.0f);
        }
    float tr[4][4];
    #pragma unroll
    for (int m = 0; m < 4; ++m)
        #pragma unroll
        for (int r = 0; r < 4; ++r)
            tr[m][r] = fmaxf(v[m][0][r], v[m][1][r]);
    #pragma unroll
    for (int off = 1; off < 16; off <<= 1)
        #pragma unroll
        for (int m = 0; m < 4; ++m)
            #pragma unroll
            for (int r = 0; r < 4; ++r)
                tr[m][r] = fmaxf(tr[m][r], __shfl_xor(tr[m][r], off));
    if (l16 == 0) {
        #pragma unroll
        for (int m = 0; m < 4; ++m)
            #pragma unroll
            for (int r = 0; r < 4; ++r)
                sred0[w][m * 16 + q * 4 + r] = tr[m][r];
    }
    __syncthreads();        // after this, Xl's A-fragments are dead
    float M[4][4];
    #pragma unroll
    for (int m = 0; m < 4; ++m)
        #pragma unroll
        for (int r = 0; r < 4; ++r) {
            int row = m * 16 + q * 4 + r;
            M[m][r] = fmaxf(fmaxf(sred0[0][row], sred0[1][row]),
                            fmaxf(sred0[2][row], sred0[3][row]));
        }
    float s[4][4];
    #pragma unroll
    for (int m = 0; m < 4; ++m)
        #pragma unroll
        for (int r = 0; r < 4; ++r) {
            float e0 = __expf(v[m][0][r] - M[m][r]);
            float e1 = __expf(v[m][1][r] - M[m][r]);
            v[m][0][r] = e0; v[m][1][r] = e1;
            s[m][r] = e0 + e1;
        }
    #pragma unroll
    for (int off = 1; off < 16; off <<= 1)
        #pragma unroll
        for (int m = 0; m < 4; ++m)
            #pragma unroll
            for (int r = 0; r < 4; ++r)
                s[m][r] += __shfl_xor(s[m][r], off);
    if (l16 == 0) {
        #pragma unroll
        for (int m = 0; m < 4; ++m)
            #pragma unroll
            for (int r = 0; r < 4; ++r)
                sred1[w][m * 16 + q * 4 + r] = s[m][r];
    }
    __syncthreads();
    // scale + stage bf16 results into Xl (row stride 136 keeps 16B alignment)
    #pragma unroll
    for (int m = 0; m < 4; ++m)
        #pragma unroll
        for (int r = 0; r < 4; ++r) {
            int row = m * 16 + q * 4 + r;
            int grow = row0 + row;
            float S = sred1[0][row] + sred1[1][row] + sred1[2][row] + sred1[3][row];
            float sc = (grow < nrows) ? inv_out[grow] / S : 0.0f;
            Xl[row * 136 + w * 32 + l16]      = bf16r(v[m][0][r] * sc);
            Xl[row * 136 + w * 32 + 16 + l16] = bf16r(v[m][1][r] * sc);
        }
    __syncthreads();
    // coalesced uint4 write-out: 64 rows x 16 uint4
    uint4* y4 = (uint4*)y;
    for (int c = threadIdx.x; c < 64 * 16; c += 256) {
        int r = c >> 4, cu = c & 15;
        int grow = row0 + r;
        if (grow < nrows) y4[(size_t)grow * 16 + cu] = *(const uint4*)&Xl[r * 136 + cu * 8];
    }
}

// ---------------------------------------------------------------------------
// Fused heads: X = concat(h, nodes) [64 rows x 256 k]; h already bf16 and
// pre-scaled by inv_r. Waves 0,1 -> mu cols; 2,3 -> logsig2 cols.
// ---------------------------------------------------------------------------
__global__ __launch_bounds__(256)
void head_mfma(const unsigned short* __restrict__ h, const float* __restrict__ nodes,
               const unsigned short* __restrict__ Wt,
               const float* __restrict__ bmu, const float* __restrict__ bls,
               float* __restrict__ out, int nrows) {
    __shared__ __align__(16) unsigned short Xl[64 * 264];
    const int row0 = blockIdx.x * 64;
    {
        const uint2* hs = (const uint2*)h;
        for (int c = threadIdx.x; c < 64 * 32; c += 256) {
            int r = c >> 5, cu = c & 31;
            int grow = row0 + r;
            uint2 v = make_uint2(0u, 0u);
            if (grow < nrows) v = hs[(size_t)grow * 32 + cu];
            *((uint2*)&Xl[r * 264] + cu) = v;
        }
    }
    for (int c = threadIdx.x; c < 64 * 32; c += 256) {
        int r = c >> 5, c4 = c & 31;
        int grow = row0 + r;
        float4 v = make_float4(0.f, 0.f, 0.f, 0.f);
        if (grow < nrows) v = *(const float4*)&nodes[(size_t)grow * 128 + c4 * 4];
        *(uint2*)&Xl[r * 264 + 128 + c4 * 4] = make_uint2(bf16pack2(v.x, v.y), bf16pack2(v.z, v.w));
    }
    __syncthreads();

    const int lane = threadIdx.x & 63;
    const int w = threadIdx.x >> 6;
    const int q = lane >> 4;
    const int l16 = lane & 15;

    short8 bf[8][2];
    #pragma unroll
    for (int k0 = 0; k0 < 8; ++k0)
        #pragma unroll
        for (int nt = 0; nt < 2; ++nt) {
            int ncol = w * 32 + nt * 16 + l16;
            bf[k0][nt] = *(const short8*)&Wt[ncol * 256 + k0 * 32 + q * 8];
        }

    f32x4 acc[4][2] = {};
    #pragma unroll
    for (int k0 = 0; k0 < 8; ++k0) {
        #pragma unroll
        for (int m = 0; m < 4; ++m) {
            short8 aa = *(const short8*)&Xl[(m * 16 + l16) * 264 + k0 * 32 + q * 8];
            acc[m][0] = __builtin_amdgcn_mfma_f32_16x16x32_bf16(aa, bf[k0][0], acc[m][0], 0, 0, 0);
            acc[m][1] = __builtin_amdgcn_mfma_f32_16x16x32_bf16(aa, bf[k0][1], acc[m][1], 0, 0, 0);
        }
    }

    const float* bb = (w < 2) ? bmu : bls;
    float* ob = (w < 2) ? out : out + (size_t)nrows * 64;
    const int c0 = (w & 1) * 32 + l16;
    const int c1 = c0 + 16;
    const float b0v = bb[c0], b1v = bb[c1];
    #pragma unroll
    for (int m = 0; m < 4; ++m)
        #pragma unroll
        for (int r = 0; r < 4; ++r) {
            int grow = row0 + m * 16 + q * 4 + r;
            if (grow < nrows) {
                ob[(size_t)grow * 64 + c0] = acc[m][0][r] + b0v;
                ob[(size_t)grow * 64 + c1] = acc[m][1][r] + b1v;
            }
        }
}

extern "C" void kernel_launch(void* const* d_in, const int* in_sizes, int n_in,
                              void* d_out, int out_size, void* d_ws, size_t ws_size,
                              hipStream_t stream) {
    const int*   senders   = (const int*)d_in[1];
    const int*   receivers = (const int*)d_in[2];
    const float* nodes = (const float*)d_in[0];
    const float* W0  = (const float*)d_in[3];
    const float* b0  = (const float*)d_in[4];
    const float* W1  = (const float*)d_in[5];
    const float* b1  = (const float*)d_in[6];
    const float* Wmu = (const float*)d_in[7];
    const float* bmu = (const float*)d_in[8];
    const float* Wls = (const float*)d_in[9];
    const float* bls = (const float*)d_in[10];
    float* out = (float*)d_out;

    const int N = N_NODES;
    const int NT = (N + 63) / 64;        // 64-row GEMM tiles

    // ws: inv_s[N] f32 | inv_r[N] f32 | buf0[N*128] bf16 | buf1[N*128] bf16 | weights
    float* inv_s = (float*)d_ws;
    float* inv_r = inv_s + N;
    unsigned short* buf0 = (unsigned short*)(inv_r + N);
    unsigned short* buf1 = buf0 + (size_t)N * 128;
    unsigned short* w0t  = buf1 + (size_t)N * 128;
    unsigned short* w1t  = w0t + 128 * 128;
    unsigned short* wht  = w1t + 128 * 128;

    // sort metadata in d_out (scratch until heads write it): offs[N+1] | srt[E]
    int* offs = (int*)d_out;
    int* srt  = offs + (N + 1);

    // setup-only temps alias buf0 (dead before layer-1 writes buf0)
    int* cnt_s  = (int*)buf0;
    int* cnt_r  = cnt_s + N;
    int* cursor = cnt_r + N;
    int* bsum   = cursor + N;

    // --- one cooperative setup kernel: zero + weight prep + hist + scan +
    //     degree factors + reorder ---
    void* args[] = {
        (void*)&senders, (void*)&receivers,
        (void*)&W0, (void*)&W1, (void*)&Wmu, (void*)&Wls,
        (void*)&w0t, (void*)&w1t, (void*)&wht,
        (void*)&cnt_s, (void*)&cnt_r, (void*)&offs, (void*)&cursor,
        (void*)&srt, (void*)&inv_s, (void*)&inv_r, (void*)&bsum
    };
    hipLaunchCooperativeKernel((void*)setup_kernel, dim3(NB_SCAN), dim3(256),
                               args, 0, stream);

    // --- layer 1 ---
    gc_mfma<false><<<NT, 256, 0, stream>>>(nodes, w0t, b0, inv_s, buf0, N);
    aggregate_kernel<<<2048, 256, 0, stream>>>((const uint4*)buf0, (uint4*)buf1,
                                               offs, srt, inv_r, N);

    // --- layer 2 (input pre-scaled bf16) ---
    gc_mfma<true><<<NT, 256, 0, stream>>>(buf1, w1t, b1, inv_s, buf0, N);
    aggregate_kernel<<<2048, 256, 0, stream>>>((const uint4*)buf0, (uint4*)buf1,
                                               offs, srt, inv_r, N);

    // --- fused heads: out = [mu | logsig2] ---
    head_mfma<<<NT, 256, 0, stream>>>(buf1, nodes, wht, bmu, bls, out, N);
}